// Round 3
// baseline (1226.390 us; speedup 1.0000x reference)
//
#include <hip/hip_runtime.h>

typedef int i32x4 __attribute__((ext_vector_type(4)));

#define AS1 __attribute__((address_space(1)))
#define AS3 __attribute__((address_space(3)))

#define M_DIM 8192
#define N_DIM 8192
#define K_DIM 2048
#define NT 32   // K-tiles of 64 bytes

// ---------------- quantize x: per-tensor scale, 16 elems/thread ----------------
__global__ __launch_bounds__(256) void quant_x_kernel(
    const float* __restrict__ x, const float* __restrict__ in_scale,
    i32x4* __restrict__ qx, int n16)
{
    int idx = blockIdx.x * 256 + threadIdx.x;
    if (idx >= n16) return;
    float s = in_scale[0];
    const float4* xp = reinterpret_cast<const float4*>(x) + (size_t)idx * 4;
    union { char c[16]; i32x4 v; } u;
#pragma unroll
    for (int v4 = 0; v4 < 4; ++v4) {
        float4 f = xp[v4];
        u.c[v4*4+0] = (char)(int)fminf(fmaxf(rintf(f.x / s), -128.f), 127.f);
        u.c[v4*4+1] = (char)(int)fminf(fmaxf(rintf(f.y / s), -128.f), 127.f);
        u.c[v4*4+2] = (char)(int)fminf(fmaxf(rintf(f.z / s), -128.f), 127.f);
        u.c[v4*4+3] = (char)(int)fminf(fmaxf(rintf(f.w / s), -128.f), 127.f);
    }
    qx[idx] = u.v;
}

// ---------------- quantize w: per-row (out-channel) scale ----------------
__global__ __launch_bounds__(256) void quant_w_kernel(
    const float* __restrict__ w, const float* __restrict__ w_scale,
    i32x4* __restrict__ qw, int n16)
{
    int idx = blockIdx.x * 256 + threadIdx.x;
    if (idx >= n16) return;
    float s = w_scale[idx >> 7];   // K=2048 -> 128 threads (of 16 elems) per row
    const float4* wp = reinterpret_cast<const float4*>(w) + (size_t)idx * 4;
    union { char c[16]; i32x4 v; } u;
#pragma unroll
    for (int v4 = 0; v4 < 4; ++v4) {
        float4 f = wp[v4];
        u.c[v4*4+0] = (char)(int)fminf(fmaxf(rintf(f.x / s), -128.f), 127.f);
        u.c[v4*4+1] = (char)(int)fminf(fmaxf(rintf(f.y / s), -128.f), 127.f);
        u.c[v4*4+2] = (char)(int)fminf(fmaxf(rintf(f.z / s), -128.f), 127.f);
        u.c[v4*4+3] = (char)(int)fminf(fmaxf(rintf(f.w / s), -128.f), 127.f);
    }
    qw[idx] = u.v;
}

// ---------------- per-out-channel combined scale + dequantized bias ----------------
__global__ __launch_bounds__(256) void prep_kernel(
    const float* __restrict__ bias, const float* __restrict__ in_scale,
    const float* __restrict__ w_scale, const float* __restrict__ b_scale,
    float* __restrict__ oscale, float* __restrict__ obias, int n)
{
    int i = blockIdx.x * 256 + threadIdx.x;
    if (i >= n) return;
    oscale[i] = in_scale[0] * w_scale[i] * 0.5f;   // W_ALPHA
    float bs = b_scale[i];
    float q = fminf(fmaxf(rintf(bias[i] / bs), -128.f), 127.f);
    obias[i] = q * bs * 0.75f;                      // B_BETA
}

// ---------------- int8 GEMM: 256x256 tile, 2-deep ring, 2 blocks/CU ----------------
// 8 waves (2M x 4N), per-wave 128x64 output = 8x4 frags of mfma_i32_16x16x64_i8.
// K-tile = 64 bytes. LDS: 2 bufs x (A 16KB + B 16KB) = 64 KiB -> 2 blocks/CU.
// Swizzle: 16B-slot' = kg ^ ((row>>1)&3), inverse-swizzled global src (rule 21).
// Ring safety: STAGE(tt+1) issued AFTER barrier tt; buffer (tt+1)&1 was consumed
// (all waves' MFMAs read it) before any wave passed barrier tt.
__global__ __launch_bounds__(512, 4) void gemm_i8_kernel(
    const char* __restrict__ qx,   // [M][K] int8
    const char* __restrict__ qw,   // [N][K] int8
    const float* __restrict__ oscale,
    const float* __restrict__ obias,
    float* __restrict__ out)       // [M][N] fp32
{
    __shared__ __align__(16) char ldsA[2 * 16384];
    __shared__ __align__(16) char ldsB[2 * 16384];

    const int t    = threadIdx.x;          // 0..511
    const int lane = t & 63;
    const int wid  = t >> 6;               // 0..7
    const int wm   = wid >> 2;             // 0..1
    const int wn   = wid & 3;              // 0..3

    // XCD-aware swizzle: 1024 blocks, 1024 % 8 == 0 -> bijective
    int bid = blockIdx.x;
    int sid = (bid & 7) * 128 + (bid >> 3);
    const size_t brow = (size_t)(sid >> 5) * 256;
    const size_t bcol = (size_t)(sid & 31) * 256;

    // staging: thread t covers LDS row t/4 (+128 on 2nd call), 16B slot t&3 (linear dest).
    // Global source pre-swizzled: logical slot = (t&3) ^ ((row>>1)&3) = (t&3) ^ ((t>>3)&3).
    const int srow  = t >> 2;
    const int lslot = (t & 3) ^ ((t >> 3) & 3);
    const char* gA = qx + (brow + srow) * K_DIM + lslot * 16;
    const char* gB = qw + (bcol + srow) * K_DIM + lslot * 16;
    char* dstA = ldsA + t * 16;
    char* dstB = ldsB + t * 16;

#define STAGE(tt_) do {                                                              \
    const int bb_ = (tt_) & 1; const int ko_ = (tt_) * 64;                           \
    __builtin_amdgcn_global_load_lds((const AS1 unsigned int*)(gA + ko_),            \
        (AS3 unsigned int*)(dstA + bb_ * 16384), 16, 0, 0);                          \
    __builtin_amdgcn_global_load_lds((const AS1 unsigned int*)(gA + ko_ + 128 * K_DIM), \
        (AS3 unsigned int*)(dstA + bb_ * 16384 + 8192), 16, 0, 0);                   \
    __builtin_amdgcn_global_load_lds((const AS1 unsigned int*)(gB + ko_),            \
        (AS3 unsigned int*)(dstB + bb_ * 16384), 16, 0, 0);                          \
    __builtin_amdgcn_global_load_lds((const AS1 unsigned int*)(gB + ko_ + 128 * K_DIM), \
        (AS3 unsigned int*)(dstB + bb_ * 16384 + 8192), 16, 0, 0);                   \
  } while (0)

    // per-lane fragment read offsets (swizzled), constant across tiles
    const int lrow = lane & 15;
    const int kg   = lane >> 4;            // 16B k-group 0..3
    int offA[8], offB[4];
#pragma unroll
    for (int m = 0; m < 8; ++m) {
        int r = wm * 128 + m * 16 + lrow;
        offA[m] = r * 64 + ((kg ^ ((r >> 1) & 3)) * 16);
    }
#pragma unroll
    for (int n = 0; n < 4; ++n) {
        int r = wn * 64 + n * 16 + lrow;
        offB[n] = r * 64 + ((kg ^ ((r >> 1) & 3)) * 16);
    }

    i32x4 acc[8][4];
#pragma unroll
    for (int m = 0; m < 8; ++m)
#pragma unroll
        for (int n = 0; n < 4; ++n)
            acc[m][n] = (i32x4){0, 0, 0, 0};

    STAGE(0);   // 4 loads in flight

    for (int tt = 0; tt < NT; ++tt) {
        // tile tt's loads were issued one full compute phase ago (or just above
        // for tt==0); drain them, then barrier so every wave sees the buffer.
        asm volatile("s_waitcnt vmcnt(0)" ::: "memory");
        __builtin_amdgcn_s_barrier();
        asm volatile("" ::: "memory");
        __builtin_amdgcn_sched_barrier(0);

        // prefetch next tile into the buffer consumed before the barrier above;
        // its ~500cy latency hides under this tile's ds_reads + 32 MFMAs.
        if (tt + 1 < NT) STAGE(tt + 1);
        __builtin_amdgcn_sched_barrier(0);

        const char* bA = ldsA + (tt & 1) * 16384;
        const char* bB = ldsB + (tt & 1) * 16384;
        i32x4 aF[8], bF[4];
#pragma unroll
        for (int m = 0; m < 8; ++m) aF[m] = *(const i32x4*)(bA + offA[m]);
#pragma unroll
        for (int n = 0; n < 4; ++n) bF[n] = *(const i32x4*)(bB + offB[n]);

        __builtin_amdgcn_s_setprio(1);
#pragma unroll
        for (int m = 0; m < 8; ++m)
#pragma unroll
            for (int n = 0; n < 4; ++n)
                acc[m][n] = __builtin_amdgcn_mfma_i32_16x16x64_i8(aF[m], bF[n], acc[m][n], 0, 0, 0);
        __builtin_amdgcn_s_setprio(0);
    }
#undef STAGE

    // epilogue: C/D layout col = lane&15, row = (lane>>4)*4 + j
    const int colq = lane & 15;
    const int rowq = lane >> 4;
#pragma unroll
    for (int n = 0; n < 4; ++n) {
        size_t col = bcol + wn * 64 + n * 16 + colq;
        float sc = oscale[col];
        float bi = obias[col];
#pragma unroll
        for (int m = 0; m < 8; ++m) {
            size_t rbase = brow + wm * 128 + m * 16 + (size_t)rowq * 4;
#pragma unroll
            for (int j = 0; j < 4; ++j)
                out[(rbase + j) * N_DIM + col] = (float)acc[m][n][j] * sc + bi;
        }
    }
}

extern "C" void kernel_launch(void* const* d_in, const int* in_sizes, int n_in,
                              void* d_out, int out_size, void* d_ws, size_t ws_size,
                              hipStream_t stream) {
    const float* x        = (const float*)d_in[0];
    const float* weight   = (const float*)d_in[1];
    const float* bias     = (const float*)d_in[2];
    const float* in_scale = (const float*)d_in[3];
    const float* w_scale  = (const float*)d_in[4];
    const float* b_scale  = (const float*)d_in[5];
    float* out = (float*)d_out;

    char* ws = (char*)d_ws;
    const size_t xk = (size_t)M_DIM * K_DIM;
    const size_t wk = (size_t)N_DIM * K_DIM;
    char*  qx     = ws;
    char*  qw     = ws + xk;
    float* oscale = (float*)(ws + xk + wk);
    float* obias  = oscale + N_DIM;

    const int n16 = (int)(xk / 16);   // 1,048,576 = 4096 * 256
    quant_x_kernel<<<4096, 256, 0, stream>>>(x, in_scale, (i32x4*)qx, n16);
    quant_w_kernel<<<4096, 256, 0, stream>>>(weight, w_scale, (i32x4*)qw, n16);
    prep_kernel<<<32, 256, 0, stream>>>(bias, in_scale, w_scale, b_scale, oscale, obias, N_DIM);

    gemm_i8_kernel<<<1024, 512, 0, stream>>>(qx, qw, oscale, obias, out);
}

// Round 4
// 246.569 us; speedup vs baseline: 4.9738x; 4.9738x over previous
//
#include <hip/hip_runtime.h>

typedef int i32x4 __attribute__((ext_vector_type(4)));

#define AS1 __attribute__((address_space(1)))
#define AS3 __attribute__((address_space(3)))

#define M_DIM 8192
#define N_DIM 8192
#define K_DIM 2048
#define NT 32   // K-tiles of 64 bytes

// ---------------- quantize x: per-tensor scale, 16 elems/thread ----------------
__global__ __launch_bounds__(256) void quant_x_kernel(
    const float* __restrict__ x, const float* __restrict__ in_scale,
    i32x4* __restrict__ qx, int n16)
{
    int idx = blockIdx.x * 256 + threadIdx.x;
    if (idx >= n16) return;
    float s = in_scale[0];
    const float4* xp = reinterpret_cast<const float4*>(x) + (size_t)idx * 4;
    union { char c[16]; i32x4 v; } u;
#pragma unroll
    for (int v4 = 0; v4 < 4; ++v4) {
        float4 f = xp[v4];
        u.c[v4*4+0] = (char)(int)fminf(fmaxf(rintf(f.x / s), -128.f), 127.f);
        u.c[v4*4+1] = (char)(int)fminf(fmaxf(rintf(f.y / s), -128.f), 127.f);
        u.c[v4*4+2] = (char)(int)fminf(fmaxf(rintf(f.z / s), -128.f), 127.f);
        u.c[v4*4+3] = (char)(int)fminf(fmaxf(rintf(f.w / s), -128.f), 127.f);
    }
    qx[idx] = u.v;
}

// ---------------- quantize w: per-row (out-channel) scale ----------------
__global__ __launch_bounds__(256) void quant_w_kernel(
    const float* __restrict__ w, const float* __restrict__ w_scale,
    i32x4* __restrict__ qw, int n16)
{
    int idx = blockIdx.x * 256 + threadIdx.x;
    if (idx >= n16) return;
    float s = w_scale[idx >> 7];   // K=2048 -> 128 threads (of 16 elems) per row
    const float4* wp = reinterpret_cast<const float4*>(w) + (size_t)idx * 4;
    union { char c[16]; i32x4 v; } u;
#pragma unroll
    for (int v4 = 0; v4 < 4; ++v4) {
        float4 f = wp[v4];
        u.c[v4*4+0] = (char)(int)fminf(fmaxf(rintf(f.x / s), -128.f), 127.f);
        u.c[v4*4+1] = (char)(int)fminf(fmaxf(rintf(f.y / s), -128.f), 127.f);
        u.c[v4*4+2] = (char)(int)fminf(fmaxf(rintf(f.z / s), -128.f), 127.f);
        u.c[v4*4+3] = (char)(int)fminf(fmaxf(rintf(f.w / s), -128.f), 127.f);
    }
    qw[idx] = u.v;
}

// ---------------- per-out-channel combined scale + dequantized bias ----------------
__global__ __launch_bounds__(256) void prep_kernel(
    const float* __restrict__ bias, const float* __restrict__ in_scale,
    const float* __restrict__ w_scale, const float* __restrict__ b_scale,
    float* __restrict__ oscale, float* __restrict__ obias, int n)
{
    int i = blockIdx.x * 256 + threadIdx.x;
    if (i >= n) return;
    oscale[i] = in_scale[0] * w_scale[i] * 0.5f;   // W_ALPHA
    float bs = b_scale[i];
    float q = fminf(fmaxf(rintf(bias[i] / bs), -128.f), 127.f);
    obias[i] = q * bs * 0.75f;                      // B_BETA
}

// ---------------- int8 GEMM: 256x256 tile, 4-deep ring, 4-phase interleave ----------------
// 8 waves (2M x 4N), per-wave 128x64 output = 8x4 frags of mfma_i32_16x16x64_i8.
// K-tile = 64 bytes. LDS: 4 bufs x (A 16KB + B 16KB) = 128 KiB (1 block/CU).
// Swizzle: 16B-slot' = kg ^ ((row>>1)&3), inverse-swizzled global src (rule 21) -> 0 conflicts.
// Schedule (m201-style): per K-tile 4 phases, each {ds_read frag subtile; 1 prefetch
// call for tile tt+2; s_barrier; lgkmcnt(0); setprio(1); 8 MFMA; setprio(0); s_barrier}.
// vmcnt gate (4, never 0 mid-loop) at end of phase 3, before closing barrier.
// NOTE: min-waves-per-EU MUST be 2 — acc[8][4]=128 regs; bound of 4 spills (R3: 6x regress).
__global__ __launch_bounds__(512, 2) void gemm_i8_kernel(
    const char* __restrict__ qx,   // [M][K] int8
    const char* __restrict__ qw,   // [N][K] int8
    const float* __restrict__ oscale,
    const float* __restrict__ obias,
    float* __restrict__ out)       // [M][N] fp32
{
    __shared__ __align__(16) char ldsA[4 * 16384];
    __shared__ __align__(16) char ldsB[4 * 16384];

    const int t    = threadIdx.x;          // 0..511
    const int lane = t & 63;
    const int wid  = t >> 6;               // 0..7
    const int wm   = wid >> 2;             // 0..1
    const int wn   = wid & 3;              // 0..3

    // XCD-aware swizzle: 1024 blocks, 1024 % 8 == 0 -> bijective
    int bid = blockIdx.x;
    int sid = (bid & 7) * 128 + (bid >> 3);
    const size_t brow = (size_t)(sid >> 5) * 256;
    const size_t bcol = (size_t)(sid & 31) * 256;

    // staging: thread t covers LDS row t/4 (+128 on _HI call), 16B slot t&3 (linear dest).
    // Global source pre-swizzled: logical slot = (t&3) ^ ((row>>1)&3) = (t&3) ^ ((t>>3)&3).
    const int srow  = t >> 2;
    const int lslot = (t & 3) ^ ((t >> 3) & 3);
    const char* gA = qx + (brow + srow) * K_DIM + lslot * 16;
    const char* gB = qw + (bcol + srow) * K_DIM + lslot * 16;
    char* dstA = ldsA + t * 16;
    char* dstB = ldsB + t * 16;

#define SA_LO(tt_) __builtin_amdgcn_global_load_lds((const AS1 unsigned int*)(gA + (tt_) * 64), \
        (AS3 unsigned int*)(dstA + ((tt_) & 3) * 16384), 16, 0, 0)
#define SA_HI(tt_) __builtin_amdgcn_global_load_lds((const AS1 unsigned int*)(gA + (tt_) * 64 + 128 * K_DIM), \
        (AS3 unsigned int*)(dstA + ((tt_) & 3) * 16384 + 8192), 16, 0, 0)
#define SB_LO(tt_) __builtin_amdgcn_global_load_lds((const AS1 unsigned int*)(gB + (tt_) * 64), \
        (AS3 unsigned int*)(dstB + ((tt_) & 3) * 16384), 16, 0, 0)
#define SB_HI(tt_) __builtin_amdgcn_global_load_lds((const AS1 unsigned int*)(gB + (tt_) * 64 + 128 * K_DIM), \
        (AS3 unsigned int*)(dstB + ((tt_) & 3) * 16384 + 8192), 16, 0, 0)
#define STAGE4(tt_) do { SA_LO(tt_); SA_HI(tt_); SB_LO(tt_); SB_HI(tt_); } while (0)

    // per-lane fragment read offsets (swizzled), constant across tiles
    const int lrow = lane & 15;
    const int kg   = lane >> 4;            // 16B k-group 0..3
    int offA[8], offB[4];
#pragma unroll
    for (int m = 0; m < 8; ++m) {
        int r = wm * 128 + m * 16 + lrow;
        offA[m] = r * 64 + ((kg ^ ((r >> 1) & 3)) * 16);
    }
#pragma unroll
    for (int n = 0; n < 4; ++n) {
        int r = wn * 64 + n * 16 + lrow;
        offB[n] = r * 64 + ((kg ^ ((r >> 1) & 3)) * 16);
    }

    i32x4 acc[8][4];
#pragma unroll
    for (int m = 0; m < 8; ++m)
#pragma unroll
        for (int n = 0; n < 4; ++n)
            acc[m][n] = (i32x4){0, 0, 0, 0};

#define MM(m_, n_, a_, b_) acc[m_][n_] = __builtin_amdgcn_mfma_i32_16x16x64_i8((a_), (b_), acc[m_][n_], 0, 0, 0)
#define BAR() __builtin_amdgcn_s_barrier()
#define LGKM0() do { asm volatile("s_waitcnt lgkmcnt(0)" ::: "memory"); __builtin_amdgcn_sched_barrier(0); } while (0)

    // prologue: tiles 0 and 1 in flight; gate tile 0 (keep tile 1's 4 calls in flight)
    STAGE4(0);
    STAGE4(1);
    asm volatile("s_waitcnt vmcnt(4)" ::: "memory");
    BAR();

    for (int tt = 0; tt < NT; ++tt) {
        const char* bA = ldsA + (tt & 3) * 16384;
        const char* bB = ldsB + (tt & 3) * 16384;
        const bool pf = (tt + 2) < NT;

        // ---- Phase 0: a0-3, b0-1 ; MFMA m0..3 x n0..1
        i32x4 a0 = *(const i32x4*)(bA + offA[0]);
        i32x4 a1 = *(const i32x4*)(bA + offA[1]);
        i32x4 a2 = *(const i32x4*)(bA + offA[2]);
        i32x4 a3 = *(const i32x4*)(bA + offA[3]);
        i32x4 b0 = *(const i32x4*)(bB + offB[0]);
        i32x4 b1 = *(const i32x4*)(bB + offB[1]);
        if (pf) SA_LO(tt + 2);
        BAR();
        LGKM0();
        __builtin_amdgcn_s_setprio(1);
        MM(0,0,a0,b0); MM(0,1,a0,b1); MM(1,0,a1,b0); MM(1,1,a1,b1);
        MM(2,0,a2,b0); MM(2,1,a2,b1); MM(3,0,a3,b0); MM(3,1,a3,b1);
        __builtin_amdgcn_s_setprio(0);
        BAR();

        // ---- Phase 1: b2-3 ; MFMA m0..3 x n2..3
        i32x4 b2 = *(const i32x4*)(bB + offB[2]);
        i32x4 b3 = *(const i32x4*)(bB + offB[3]);
        if (pf) SA_HI(tt + 2);
        BAR();
        LGKM0();
        __builtin_amdgcn_s_setprio(1);
        MM(0,2,a0,b2); MM(0,3,a0,b3); MM(1,2,a1,b2); MM(1,3,a1,b3);
        MM(2,2,a2,b2); MM(2,3,a2,b3); MM(3,2,a3,b2); MM(3,3,a3,b3);
        __builtin_amdgcn_s_setprio(0);
        BAR();

        // ---- Phase 2: a4-7 ; MFMA m4..7 x n0..1
        i32x4 a4 = *(const i32x4*)(bA + offA[4]);
        i32x4 a5 = *(const i32x4*)(bA + offA[5]);
        i32x4 a6 = *(const i32x4*)(bA + offA[6]);
        i32x4 a7 = *(const i32x4*)(bA + offA[7]);
        if (pf) SB_LO(tt + 2);
        BAR();
        LGKM0();
        __builtin_amdgcn_s_setprio(1);
        MM(4,0,a4,b0); MM(4,1,a4,b1); MM(5,0,a5,b0); MM(5,1,a5,b1);
        MM(6,0,a6,b0); MM(6,1,a6,b1); MM(7,0,a7,b0); MM(7,1,a7,b1);
        __builtin_amdgcn_s_setprio(0);
        BAR();

        // ---- Phase 3: no ds_read ; MFMA m4..7 x n2..3 ; tile gate before closing BAR
        if (pf) SB_HI(tt + 2);
        BAR();
        __builtin_amdgcn_s_setprio(1);
        MM(4,2,a4,b2); MM(4,3,a4,b3); MM(5,2,a5,b2); MM(5,3,a5,b3);
        MM(6,2,a6,b2); MM(6,3,a6,b3); MM(7,2,a7,b2); MM(7,3,a7,b3);
        __builtin_amdgcn_s_setprio(0);
        if (tt + 1 < NT) {
            if (tt + 2 < NT) asm volatile("s_waitcnt vmcnt(4)" ::: "memory");
            else             asm volatile("s_waitcnt vmcnt(0)" ::: "memory");
            BAR();   // closing barrier doubles as next tile's data-visibility gate
        }
    }
#undef STAGE4
#undef SA_LO
#undef SA_HI
#undef SB_LO
#undef SB_HI
#undef MM
#undef BAR
#undef LGKM0

    // epilogue: C/D layout col = lane&15, row = (lane>>4)*4 + j
    const int colq = lane & 15;
    const int rowq = lane >> 4;
#pragma unroll
    for (int n = 0; n < 4; ++n) {
        size_t col = bcol + wn * 64 + n * 16 + colq;
        float sc = oscale[col];
        float bi = obias[col];
#pragma unroll
        for (int m = 0; m < 8; ++m) {
            size_t rbase = brow + wm * 128 + m * 16 + (size_t)rowq * 4;
#pragma unroll
            for (int j = 0; j < 4; ++j)
                out[(rbase + j) * N_DIM + col] = (float)acc[m][n][j] * sc + bi;
        }
    }
}

extern "C" void kernel_launch(void* const* d_in, const int* in_sizes, int n_in,
                              void* d_out, int out_size, void* d_ws, size_t ws_size,
                              hipStream_t stream) {
    const float* x        = (const float*)d_in[0];
    const float* weight   = (const float*)d_in[1];
    const float* bias     = (const float*)d_in[2];
    const float* in_scale = (const float*)d_in[3];
    const float* w_scale  = (const float*)d_in[4];
    const float* b_scale  = (const float*)d_in[5];
    float* out = (float*)d_out;

    char* ws = (char*)d_ws;
    const size_t xk = (size_t)M_DIM * K_DIM;
    const size_t wk = (size_t)N_DIM * K_DIM;
    char*  qx     = ws;
    char*  qw     = ws + xk;
    float* oscale = (float*)(ws + xk + wk);
    float* obias  = oscale + N_DIM;

    const int n16 = (int)(xk / 16);   // 1,048,576 = 4096 * 256
    quant_x_kernel<<<4096, 256, 0, stream>>>(x, in_scale, (i32x4*)qx, n16);
    quant_w_kernel<<<4096, 256, 0, stream>>>(weight, w_scale, (i32x4*)qw, n16);
    prep_kernel<<<32, 256, 0, stream>>>(bias, in_scale, w_scale, b_scale, oscale, obias, N_DIM);

    gemm_i8_kernel<<<1024, 512, 0, stream>>>(qx, qw, oscale, obias, out);
}

// Round 5
// 239.526 us; speedup vs baseline: 5.1201x; 1.0294x over previous
//
#include <hip/hip_runtime.h>

typedef int i32x4 __attribute__((ext_vector_type(4)));

#define AS1 __attribute__((address_space(1)))
#define AS3 __attribute__((address_space(3)))

#define M_DIM 8192
#define N_DIM 8192
#define K_DIM 2048
#define NT 32   // K-tiles of 64 bytes

// ---------------- quantize x: per-tensor scale, 16 elems/thread ----------------
__global__ __launch_bounds__(256) void quant_x_kernel(
    const float* __restrict__ x, const float* __restrict__ in_scale,
    i32x4* __restrict__ qx, int n16)
{
    int idx = blockIdx.x * 256 + threadIdx.x;
    if (idx >= n16) return;
    float s = in_scale[0];
    const float4* xp = reinterpret_cast<const float4*>(x) + (size_t)idx * 4;
    union { char c[16]; i32x4 v; } u;
#pragma unroll
    for (int v4 = 0; v4 < 4; ++v4) {
        float4 f = xp[v4];
        u.c[v4*4+0] = (char)(int)fminf(fmaxf(rintf(f.x / s), -128.f), 127.f);
        u.c[v4*4+1] = (char)(int)fminf(fmaxf(rintf(f.y / s), -128.f), 127.f);
        u.c[v4*4+2] = (char)(int)fminf(fmaxf(rintf(f.z / s), -128.f), 127.f);
        u.c[v4*4+3] = (char)(int)fminf(fmaxf(rintf(f.w / s), -128.f), 127.f);
    }
    qx[idx] = u.v;
}

// ---------------- quantize w: per-row (out-channel) scale ----------------
__global__ __launch_bounds__(256) void quant_w_kernel(
    const float* __restrict__ w, const float* __restrict__ w_scale,
    i32x4* __restrict__ qw, int n16)
{
    int idx = blockIdx.x * 256 + threadIdx.x;
    if (idx >= n16) return;
    float s = w_scale[idx >> 7];   // K=2048 -> 128 threads (of 16 elems) per row
    const float4* wp = reinterpret_cast<const float4*>(w) + (size_t)idx * 4;
    union { char c[16]; i32x4 v; } u;
#pragma unroll
    for (int v4 = 0; v4 < 4; ++v4) {
        float4 f = wp[v4];
        u.c[v4*4+0] = (char)(int)fminf(fmaxf(rintf(f.x / s), -128.f), 127.f);
        u.c[v4*4+1] = (char)(int)fminf(fmaxf(rintf(f.y / s), -128.f), 127.f);
        u.c[v4*4+2] = (char)(int)fminf(fmaxf(rintf(f.z / s), -128.f), 127.f);
        u.c[v4*4+3] = (char)(int)fminf(fmaxf(rintf(f.w / s), -128.f), 127.f);
    }
    qw[idx] = u.v;
}

// ---------------- per-out-channel combined scale + dequantized bias ----------------
__global__ __launch_bounds__(256) void prep_kernel(
    const float* __restrict__ bias, const float* __restrict__ in_scale,
    const float* __restrict__ w_scale, const float* __restrict__ b_scale,
    float* __restrict__ oscale, float* __restrict__ obias, int n)
{
    int i = blockIdx.x * 256 + threadIdx.x;
    if (i >= n) return;
    oscale[i] = in_scale[0] * w_scale[i] * 0.5f;   // W_ALPHA
    float bs = b_scale[i];
    float q = fminf(fmaxf(rintf(bias[i] / bs), -128.f), 127.f);
    obias[i] = q * bs * 0.75f;                      // B_BETA
}

// ---------------- int8 GEMM: 256x256 tile, 4-deep ring, m201 cadence ----------------
// 8 waves (2M x 4N), per-wave 128x64 output = 8x4 frags of mfma_i32_16x16x64_i8.
// 2 K-tiles/iter, 2 phases/K-tile, 16 MFMA per phase (m201's cluster size).
// LDS: 4 bufs x (A 16KB + B 16KB) = 128 KiB. Swizzle slot' = kg ^ ((row>>1)&3),
// inverse-swizzled global src (rule 21) -> 0 bank conflicts (verified R2).
// vmcnt(4) counted gates, once per K-tile; never 0 mid-loop; last iter peeled.
// NOTE: min-waves-per-EU MUST be 2 — acc=128 AGPR; bound of 4 spills (R3: 6x regress).
__global__ __launch_bounds__(512, 2) void gemm_i8_kernel(
    const char* __restrict__ qx,   // [M][K] int8
    const char* __restrict__ qw,   // [N][K] int8
    const float* __restrict__ oscale,
    const float* __restrict__ obias,
    float* __restrict__ out)       // [M][N] fp32
{
    __shared__ __align__(16) char ldsA[4 * 16384];
    __shared__ __align__(16) char ldsB[4 * 16384];

    const int t    = threadIdx.x;          // 0..511
    const int lane = t & 63;
    const int wid  = t >> 6;               // 0..7
    const int wm   = wid >> 2;             // 0..1
    const int wn   = wid & 3;              // 0..3

    // XCD-aware swizzle: 1024 blocks, 1024 % 8 == 0 -> bijective
    int bid = blockIdx.x;
    int sid = (bid & 7) * 128 + (bid >> 3);
    const size_t brow = (size_t)(sid >> 5) * 256;
    const size_t bcol = (size_t)(sid & 31) * 256;

    // staging: thread t covers LDS row t/4 (+128 on _HI), 16B slot t&3 (linear dest).
    // Global source pre-swizzled: logical slot = (t&3) ^ ((row>>1)&3) = (t&3) ^ ((t>>3)&3).
    const int srow  = t >> 2;
    const int lslot = (t & 3) ^ ((t >> 3) & 3);
    const char* gA = qx + (brow + srow) * K_DIM + lslot * 16;
    const char* gB = qw + (bcol + srow) * K_DIM + lslot * 16;
    char* dstA = ldsA + t * 16;
    char* dstB = ldsB + t * 16;

#define SA_LO(tt_) __builtin_amdgcn_global_load_lds((const AS1 unsigned int*)(gA + (tt_) * 64), \
        (AS3 unsigned int*)(dstA + ((tt_) & 3) * 16384), 16, 0, 0)
#define SA_HI(tt_) __builtin_amdgcn_global_load_lds((const AS1 unsigned int*)(gA + (tt_) * 64 + 128 * K_DIM), \
        (AS3 unsigned int*)(dstA + ((tt_) & 3) * 16384 + 8192), 16, 0, 0)
#define SB_LO(tt_) __builtin_amdgcn_global_load_lds((const AS1 unsigned int*)(gB + (tt_) * 64), \
        (AS3 unsigned int*)(dstB + ((tt_) & 3) * 16384), 16, 0, 0)
#define SB_HI(tt_) __builtin_amdgcn_global_load_lds((const AS1 unsigned int*)(gB + (tt_) * 64 + 128 * K_DIM), \
        (AS3 unsigned int*)(dstB + ((tt_) & 3) * 16384 + 8192), 16, 0, 0)

    // per-lane fragment read offsets (swizzled), constant across tiles
    const int lrow = lane & 15;
    const int kg   = lane >> 4;            // 16B k-group 0..3
    int offA[8], offB[4];
#pragma unroll
    for (int m = 0; m < 8; ++m) {
        int r = wm * 128 + m * 16 + lrow;
        offA[m] = r * 64 + ((kg ^ ((r >> 1) & 3)) * 16);
    }
#pragma unroll
    for (int n = 0; n < 4; ++n) {
        int r = wn * 64 + n * 16 + lrow;
        offB[n] = r * 64 + ((kg ^ ((r >> 1) & 3)) * 16);
    }

    i32x4 acc[8][4];
#pragma unroll
    for (int m = 0; m < 8; ++m)
#pragma unroll
        for (int n = 0; n < 4; ++n)
            acc[m][n] = (i32x4){0, 0, 0, 0};

#define MM(m_, n_, a_, b_) acc[m_][n_] = __builtin_amdgcn_mfma_i32_16x16x64_i8((a_), (b_), acc[m_][n_], 0, 0, 0)
#define BAR() do { __builtin_amdgcn_s_barrier(); asm volatile("" ::: "memory"); } while (0)
#define LGKM0() do { asm volatile("s_waitcnt lgkmcnt(0)" ::: "memory"); __builtin_amdgcn_sched_barrier(0); } while (0)
#define VMCNT(n_) asm volatile("s_waitcnt vmcnt(" #n_ ")" ::: "memory")

    // One K-tile = 2 phases of 16 MFMA. pfa_/pfb_: prefetch tile (-1 = none).
    // gate8_: 1 -> vmcnt(4) in phase b (steady), 0 -> vmcnt(0) (final drain).
#define KTILE(tt_, pfa_, pfb_, gate_)  do {                                          \
    const char* bA = ldsA + ((tt_) & 3) * 16384;                                     \
    const char* bB = ldsB + ((tt_) & 3) * 16384;                                     \
    /* phase a: 8 ds_read + 2 prefetch; MFMA m0-3 x n0-3 */                          \
    i32x4 a0 = *(const i32x4*)(bA + offA[0]);                                        \
    i32x4 a1 = *(const i32x4*)(bA + offA[1]);                                        \
    i32x4 a2 = *(const i32x4*)(bA + offA[2]);                                        \
    i32x4 a3 = *(const i32x4*)(bA + offA[3]);                                        \
    i32x4 b0 = *(const i32x4*)(bB + offB[0]);                                        \
    i32x4 b1 = *(const i32x4*)(bB + offB[1]);                                        \
    i32x4 b2 = *(const i32x4*)(bB + offB[2]);                                        \
    i32x4 b3 = *(const i32x4*)(bB + offB[3]);                                        \
    if ((pfa_) >= 0) { SA_LO(pfa_); SA_HI(pfa_); }                                   \
    BAR();                                                                           \
    LGKM0();                                                                         \
    __builtin_amdgcn_s_setprio(1);                                                   \
    MM(0,0,a0,b0); MM(0,1,a0,b1); MM(0,2,a0,b2); MM(0,3,a0,b3);                      \
    MM(1,0,a1,b0); MM(1,1,a1,b1); MM(1,2,a1,b2); MM(1,3,a1,b3);                      \
    MM(2,0,a2,b0); MM(2,1,a2,b1); MM(2,2,a2,b2); MM(2,3,a2,b3);                      \
    MM(3,0,a3,b0); MM(3,1,a3,b1); MM(3,2,a3,b2); MM(3,3,a3,b3);                      \
    __builtin_amdgcn_s_setprio(0);                                                   \
    BAR();                                                                           \
    /* phase b: 4 ds_read + 2 prefetch; gate; MFMA m4-7 x n0-3 */                    \
    a0 = *(const i32x4*)(bA + offA[4]);                                              \
    a1 = *(const i32x4*)(bA + offA[5]);                                              \
    a2 = *(const i32x4*)(bA + offA[6]);                                              \
    a3 = *(const i32x4*)(bA + offA[7]);                                              \
    if ((pfb_) >= 0) { SB_LO(pfb_); SB_HI(pfb_); }                                   \
    if (gate_) { VMCNT(4); } else { VMCNT(0); }                                      \
    BAR();                                                                           \
    LGKM0();                                                                         \
    __builtin_amdgcn_s_setprio(1);                                                   \
    MM(4,0,a0,b0); MM(4,1,a0,b1); MM(4,2,a0,b2); MM(4,3,a0,b3);                      \
    MM(5,0,a1,b0); MM(5,1,a1,b1); MM(5,2,a1,b2); MM(5,3,a1,b3);                      \
    MM(6,0,a2,b0); MM(6,1,a2,b1); MM(6,2,a2,b2); MM(6,3,a2,b3);                      \
    MM(7,0,a3,b0); MM(7,1,a3,b1); MM(7,2,a3,b2); MM(7,3,a3,b3);                      \
    __builtin_amdgcn_s_setprio(0);                                                   \
    BAR();                                                                           \
  } while (0)

    // prologue: tiles 0,1 in flight; gate tile 0 (tile 1's 4 calls stay in flight)
    SA_LO(0); SA_HI(0); SB_LO(0); SB_HI(0);
    SA_LO(1); SA_HI(1); SB_LO(1); SB_HI(1);
    VMCNT(4);
    BAR();

    // main loop: iterations 0..14 (tiles 0..29); prefetch t0+2 in tile t0's phases,
    // t0+3 in tile t1's phases. Gates: t1-phase-b drains t0+2-3... see ledger:
    //   tile t0 phase b: outstanding = t1(old 4) + p0(new 4) -> vmcnt(4) drains t1.
    //   tile t1 phase b: outstanding = p0(4) + p1(4)        -> vmcnt(4) drains p0.
    for (int it = 0; it < NT / 2 - 1; ++it) {
        const int t0 = 2 * it;
        KTILE(t0,     t0 + 2, t0 + 2, 1);
        KTILE(t0 + 1, t0 + 3, t0 + 3, 1);
    }
    // peeled final iteration: tiles 30,31 staged; entry outstanding = tile31's 4.
    KTILE(30, -1, -1, 0);   // vmcnt(0) drains tile 31 before its reads
    KTILE(31, -1, -1, 1);   // vmcnt(4) is a no-op (nothing outstanding)

#undef KTILE
#undef SA_LO
#undef SA_HI
#undef SB_LO
#undef SB_HI
#undef MM
#undef BAR
#undef LGKM0
#undef VMCNT

    // epilogue: C/D layout col = lane&15, row = (lane>>4)*4 + j
    const int colq = lane & 15;
    const int rowq = lane >> 4;
#pragma unroll
    for (int n = 0; n < 4; ++n) {
        size_t col = bcol + wn * 64 + n * 16 + colq;
        float sc = oscale[col];
        float bi = obias[col];
#pragma unroll
        for (int m = 0; m < 8; ++m) {
            size_t rbase = brow + wm * 128 + m * 16 + (size_t)rowq * 4;
#pragma unroll
            for (int j = 0; j < 4; ++j)
                out[(rbase + j) * N_DIM + col] = (float)acc[m][n][j] * sc + bi;
        }
    }
}

extern "C" void kernel_launch(void* const* d_in, const int* in_sizes, int n_in,
                              void* d_out, int out_size, void* d_ws, size_t ws_size,
                              hipStream_t stream) {
    const float* x        = (const float*)d_in[0];
    const float* weight   = (const float*)d_in[1];
    const float* bias     = (const float*)d_in[2];
    const float* in_scale = (const float*)d_in[3];
    const float* w_scale  = (const float*)d_in[4];
    const float* b_scale  = (const float*)d_in[5];
    float* out = (float*)d_out;

    char* ws = (char*)d_ws;
    const size_t xk = (size_t)M_DIM * K_DIM;
    const size_t wk = (size_t)N_DIM * K_DIM;
    char*  qx     = ws;
    char*  qw     = ws + xk;
    float* oscale = (float*)(ws + xk + wk);
    float* obias  = oscale + N_DIM;

    const int n16 = (int)(xk / 16);   // 1,048,576 = 4096 * 256
    quant_x_kernel<<<4096, 256, 0, stream>>>(x, in_scale, (i32x4*)qx, n16);
    quant_w_kernel<<<4096, 256, 0, stream>>>(weight, w_scale, (i32x4*)qw, n16);
    prep_kernel<<<32, 256, 0, stream>>>(bias, in_scale, w_scale, b_scale, oscale, obias, N_DIM);

    gemm_i8_kernel<<<1024, 512, 0, stream>>>(qx, qw, oscale, obias, out);
}